// Round 10
// baseline (245.390 us; speedup 1.0000x reference)
//
#include <hip/hip_runtime.h>

typedef _Float16 half8 __attribute__((ext_vector_type(8)));
typedef float f32x4 __attribute__((ext_vector_type(4)));

#define B_ 256
#define K_ 512
#define D_ 256
#define H_ 256
#define NROWS (B_*K_)          // 131072
#define LNEPS 1e-5f
#define ITERS 16               // row-tiles of 32 per block
#define SITERS 8               // super-iters: 2 tiles each
#define INV1024 (1.0f/1024.0f)

// LDS A layout: per 32-row tile, arrays h and l; row stride 528 B (33x16,
// bank shift 4/row); chunk c (16B, k-range [8c,8c+8)) lives at byte offset
// pos(c)*16 where pos(c) = (c>>1) + 16*(c&1). Writes (one chunk per thread)
// and reads (n16-major) are conflict-free.
#define ROWS_ 528
#define ASZ (32*ROWS_)          // 16896 per array
#define BUFSZ (2*ASZ)           // h + l = 33792 per buffer
// 4-deep tile ring (tile i -> buf i&3). LDS map:
//   bufs 4*33792 | red[2][16][32] f2 8192 | logits[512] f2 4096 | aux 128
#define RED_OFF   (4*BUFSZ)                    // 135168
#define LOG_OFF   (RED_OFF + 8192)             // 143360
#define AUX_OFF   (LOG_OFF + 4096)             // 147456
#define LDS_BYTES (AUX_OFF + 128)              // 147584 <= 160 KiB

// DPP-butterfly add (VALU pipe), row16-internal; <=1 ulp vs shfl order.
template<int CTRL>
__device__ __forceinline__ float dpp_fadd(float x) {
    const int xi = __builtin_bit_cast(int, x);
    const int pi = __builtin_amdgcn_update_dpp(0, xi, CTRL, 0xf, 0xf, true);
    return x + __builtin_bit_cast(float, pi);
}
#define DPP_XOR1  0xB1   // quad_perm(1,0,3,2)
#define DPP_XOR2  0x4E   // quad_perm(2,3,0,1)
#define DPP_ROR4  0x124  // row_ror:4
#define DPP_ROR8  0x128  // row_ror:8

// 1024 threads = 16 waves, 16 cols/wave, round-2 MFMA/epi phases verbatim.
// Super-iteration (r10): TWO tiles per barrier-pair via 4-deep buffer ring:
//   [MFMA+epi t_i -> red0 | MFMA+epi t_{i+1} -> red1 | BAR |
//    stage t_{i+2} | load t_{i+3} | finalize both (t<64) | stage t_{i+3} | BAR]
// Barrier-pairs per tile 2 -> 1. Phase discipline preserved (staging strictly
// between barriers): r4/r6/r7 evidence says this is what prevents the
// ~40-reg spill at the 128-reg cap. Do not interleave staging with MFMA.
// Fused combine tail (r8, verified).
__global__ __launch_bounds__(1024, 4) void mfma_main(
    const float* __restrict__ slots, const float* __restrict__ gamma,
    const float* __restrict__ beta,  const float* __restrict__ w1,
    const float* __restrict__ b1,    const float* __restrict__ w2,
    const float* __restrict__ b2,    const float* __restrict__ u,
    const float* __restrict__ rk,    float* __restrict__ out)
{
    extern __shared__ __align__(16) char smem[];
    float2* red    = (float2*)(smem + RED_OFF);   // [2][16][32]
    float2* logits = (float2*)(smem + LOG_OFF);   // [512]
    unsigned long long* best = (unsigned long long*)(smem + AUX_OFF);
    int* cnts = (int*)(smem + AUX_OFF + 64);      // [8]
    int* sNK  = (int*)(smem + AUX_OFF + 96);      // [0]=need [1]=kbest

    const int t    = threadIdx.x;
    const int lane = t & 63;
    const int wv   = t >> 6;        // 0..15
    const int quad = lane >> 4;     // 0..3
    const int n16  = lane & 15;
    const int srow = t >> 5;        // 0..31 staging row
    const int seg8 = t & 31;        // 8 d's (one chunk) per staging thread

    const int colB  = wv*16 + n16;  // B-frag load column (0..255)
    const int tile0 = blockIdx.x * ITERS;

    // ---- persistent B fragments (gamma folded) + b1' = b1 + beta.W1 ----
    half8 Bh[8], Bl[8];
    float bsum = 0.f;
    #pragma unroll
    for (int ks = 0; ks < 8; ++ks) {
        const int k0 = ks*32 + quad*8;
        half8 h, l;
        #pragma unroll
        for (int j = 0; j < 8; ++j) {
            const float w  = w1[(size_t)(k0 + j)*H_ + colB];
            bsum += beta[k0 + j] * w;
            const float wg = gamma[k0 + j] * w;
            const _Float16 hh = (_Float16)wg;
            h[j] = hh;
            l[j] = (_Float16)((wg - (float)hh) * 1024.0f);
        }
        Bh[ks] = h; Bl[ks] = l;
    }
    bsum += __shfl_xor(bsum, 16, 64);
    bsum += __shfl_xor(bsum, 32, 64);
    const float b1col = b1[colB] + bsum;   // valid for col colB (lane n16)

    // redistribute epilogue constants to D layout: col = base + quad*4 + reg
    float b1p[4], w20[4], w21[4];
    #pragma unroll
    for (int reg = 0; reg < 4; ++reg) {
        const int cq = quad*4 + reg;                    // 0..15
        b1p[reg] = __shfl(b1col, cq, 64);               // from lane cq
        const int col = wv*16 + cq;
        w20[reg] = w2[2*col + 0];
        w21[reg] = w2[2*col + 1];
    }

    // LN (xhat only) + fp16 split + permuted LDS store of one 32-row tile.
    auto ln_stage = [&](const float* xr, char* buf) {
        float s = 0.f;
        #pragma unroll
        for (int j = 0; j < 8; ++j) s += xr[j];
        s = dpp_fadd<DPP_XOR1>(s);
        s = dpp_fadd<DPP_XOR2>(s);
        s = dpp_fadd<DPP_ROR4>(s);
        s = dpp_fadd<DPP_ROR8>(s);
        s += __shfl_xor(s, 16, 64);
        const float mean = s * (1.f/256.f);
        float q = 0.f;
        #pragma unroll
        for (int j = 0; j < 8; ++j) { const float d = xr[j]-mean; q += d*d; }
        q = dpp_fadd<DPP_XOR1>(q);
        q = dpp_fadd<DPP_XOR2>(q);
        q = dpp_fadd<DPP_ROR4>(q);
        q = dpp_fadd<DPP_ROR8>(q);
        q += __shfl_xor(q, 16, 64);
        const float rstd = rsqrtf(q * (1.f/256.f) + LNEPS);
        half8 hh, ll;
        #pragma unroll
        for (int jj = 0; jj < 8; ++jj) {
            const float x = (xr[jj] - mean) * rstd;
            const _Float16 xh = (_Float16)x;
            hh[jj] = xh;
            ll[jj] = (_Float16)((x - (float)xh) * 1024.0f);
        }
        const int off = srow*ROWS_ + ((seg8>>1) + 16*(seg8&1)) * 16;
        *(half8*)(buf + off)       = hh;
        *(half8*)(buf + ASZ + off) = ll;
    };

    auto load_tile = [&](int tile, float* xr) {
        const float* sp = slots + ((size_t)tile*32 + srow)*D_ + seg8*8;
        #pragma unroll
        for (int i4 = 0; i4 < 2; ++i4) {
            const float4 v = ((const float4*)sp)[i4];
            xr[4*i4+0]=v.x; xr[4*i4+1]=v.y; xr[4*i4+2]=v.z; xr[4*i4+3]=v.w;
        }
    };

    // MFMA + epilogue for one tile (buffer base Ah), partials -> red[rslot]
    auto mfma_tile = [&](const char* Ah, int rslot) {
        const char* Al = Ah + ASZ;
        f32x4 Ch[2], Cl[2];
        Ch[0] = (f32x4)0.f; Ch[1] = (f32x4)0.f;
        Cl[0] = (f32x4)0.f; Cl[1] = (f32x4)0.f;
        #pragma unroll
        for (int ks = 0; ks < 8; ++ks) {
            const int c   = ks*4 + quad;                    // chunk index
            const int off = ((c>>1) + 16*(c&1)) * 16;       // pos(c)*16
            const half8 ah0 = *(const half8*)(Ah +  n16     *ROWS_ + off);
            const half8 ah1 = *(const half8*)(Ah + (n16+16) *ROWS_ + off);
            const half8 al0 = *(const half8*)(Al +  n16     *ROWS_ + off);
            const half8 al1 = *(const half8*)(Al + (n16+16) *ROWS_ + off);
            Ch[0] = __builtin_amdgcn_mfma_f32_16x16x32_f16(Bh[ks], ah0, Ch[0], 0,0,0);
            Ch[1] = __builtin_amdgcn_mfma_f32_16x16x32_f16(Bh[ks], ah1, Ch[1], 0,0,0);
            Cl[0] = __builtin_amdgcn_mfma_f32_16x16x32_f16(Bl[ks], ah0, Cl[0], 0,0,0);
            Cl[1] = __builtin_amdgcn_mfma_f32_16x16x32_f16(Bl[ks], ah1, Cl[1], 0,0,0);
            Cl[0] = __builtin_amdgcn_mfma_f32_16x16x32_f16(Bh[ks], al0, Cl[0], 0,0,0);
            Cl[1] = __builtin_amdgcn_mfma_f32_16x16x32_f16(Bh[ks], al1, Cl[1], 0,0,0);
        }
        #pragma unroll
        for (int rs = 0; rs < 2; ++rs) {
            float p0 = 0.f, p1 = 0.f;
            #pragma unroll
            for (int reg = 0; reg < 4; ++reg) {
                float hv = Ch[rs][reg] + Cl[rs][reg]*INV1024 + b1p[reg];
                hv = fmaxf(hv, 0.f);
                p0 = fmaf(hv, w20[reg], p0);
                p1 = fmaf(hv, w21[reg], p1);
            }
            p0 += __shfl_xor(p0, 16, 64); p1 += __shfl_xor(p1, 16, 64);
            p0 += __shfl_xor(p0, 32, 64); p1 += __shfl_xor(p1, 32, 64);
            if (lane < 16)                       // quad 0 holds the total
                red[rslot*512 + wv*32 + rs*16 + n16] = make_float2(p0, p1);
        }
    };

    // prologue: stage tiles 0 and 1 into bufs 0,1
    {
        float xr0[8];
        load_tile(tile0 + 0, xr0);
        ln_stage(xr0, smem);
        load_tile(tile0 + 1, xr0);
        ln_stage(xr0, smem + BUFSZ);
    }
    __syncthreads();

    for (int s = 0; s < SITERS; ++s) {
        const int i0 = 2*s;
        const bool have_next = (s + 1 < SITERS);

        // prefetch tile i0+2 (consumed after BAR1; latency hidden by MFMA)
        float xr[8];
        if (have_next)
            load_tile(tile0 + i0 + 2, xr);

        // ---- two MFMA+epi phases (bufs i0&3, (i0+1)&3) ----
        mfma_tile(smem + (size_t)(i0&3)*BUFSZ,     0);
        mfma_tile(smem + (size_t)((i0+1)&3)*BUFSZ, 1);
        __syncthreads();

        // ---- stage t_{i0+2}; issue t_{i0+3} load; finalize; stage t_{i0+3} ----
        if (have_next) {
            ln_stage(xr, smem + (size_t)((i0+2)&3)*BUFSZ);
            load_tile(tile0 + i0 + 3, xr);      // latency hidden by finalize
        }
        // finalize both tiles: wave 0's 64 lanes (tt = lane>>5, row = lane&31)
        if (t < 64) {
            const int tt  = t >> 5;
            const int r32 = t & 31;
            float p0 = 0.f, p1 = 0.f;
            #pragma unroll
            for (int w = 0; w < 16; ++w) {
                const float2 v = red[tt*512 + w*32 + r32];
                p0 += v.x; p1 += v.y;
            }
            logits[(i0 + tt)*32 + r32] = make_float2(p0, p1);
        }
        if (have_next)
            ln_stage(xr, smem + (size_t)((i0+3)&3)*BUFSZ);
        __syncthreads();
    }

    // ==== fused combine: gumbel decision, soft prob, lower-bound fixup ====
    bool keep = false;
    if (t < 512) {
        const int k = t;
        const int row = blockIdx.x*K_ + k;
        const float2 lg = logits[k];
        const float l0 = b2[0] + lg.x;
        const float l1 = b2[1] + lg.y;
        const float2 uu = ((const float2*)u)[row];
        const float g0 = -logf(-logf(uu.x));
        const float g1 = -logf(-logf(uu.y));
        keep = (l1 + g1) > (l0 + g0);
        out[NROWS + row] = 1.f / (1.f + expf(l0 - l1));

        unsigned long long comb = 0;
        if (!keep)
            comb = ((unsigned long long)__float_as_uint(rk[row]) << 32)
                 | (unsigned)(K_ - 1 - k);
        const int wcount = __popcll(__ballot(keep));
        #pragma unroll
        for (int off = 32; off >= 1; off >>= 1) {
            const unsigned long long o = __shfl_xor(comb, off, 64);
            if (o > comb) comb = o;
        }
        if ((k & 63) == 0) { best[k >> 6] = comb; cnts[k >> 6] = wcount; }
    }
    __syncthreads();
    if (t == 0) {
        int tot = 0; unsigned long long bc = 0;
        #pragma unroll
        for (int w = 0; w < 8; ++w) { tot += cnts[w]; if (best[w] > bc) bc = best[w]; }
        sNK[0] = (tot == 0);
        sNK[1] = (K_ - 1) - (int)(bc & 0xffffffffu);
    }
    __syncthreads();
    if (t < 512) {
        const int row = blockIdx.x*K_ + t;
        const bool m = keep || (sNK[0] && (t == sNK[1]));
        out[row] = m ? 1.f : 0.f;
    }
}

extern "C" void kernel_launch(void* const* d_in, const int* in_sizes, int n_in,
                              void* d_out, int out_size, void* d_ws, size_t ws_size,
                              hipStream_t stream) {
    const float* slots = (const float*)d_in[0];
    const float* gamma = (const float*)d_in[1];
    const float* beta  = (const float*)d_in[2];
    const float* w1    = (const float*)d_in[3];
    const float* b1    = (const float*)d_in[4];
    const float* w2    = (const float*)d_in[5];
    const float* b2    = (const float*)d_in[6];
    const float* u     = (const float*)d_in[7];
    const float* rk    = (const float*)d_in[8];
    float* out = (float*)d_out;

    hipLaunchKernelGGL(mfma_main, dim3(B_), dim3(1024), LDS_BYTES, stream,
                       slots, gamma, beta, w1, b1, w2, b2, u, rk, out);
}

// Round 11
// 226.206 us; speedup vs baseline: 1.0848x; 1.0848x over previous
//
#include <hip/hip_runtime.h>

typedef _Float16 half8 __attribute__((ext_vector_type(8)));
typedef float f32x4 __attribute__((ext_vector_type(4)));

#define B_ 256
#define K_ 512
#define D_ 256
#define H_ 256
#define NROWS (B_*K_)          // 131072
#define LNEPS 1e-5f
#define ITERS 16               // row-tiles of 32 per block
#define INV1024 (1.0f/1024.0f)

// LDS A layout: per 32-row tile, arrays h and l; row stride 528 B (33x16,
// bank shift 4/row); chunk c (16B, k-range [8c,8c+8)) lives at byte offset
// pos(c)*16 where pos(c) = (c>>1) + 16*(c&1). Writes (one chunk per thread)
// and reads (n16-major) are conflict-free.
#define ROWS_ 528
#define ASZ (32*ROWS_)          // 16896 per array
#define BUFSZ (2*ASZ)           // h + l = 33792 per buffer
// red[16][33] float2 (stride 33 -> w-major parallel reads are 2-way max):
// bank(w,r) = (66w+2r)%32 = (2w+2r)%32 -> 16 lanes (w=0..15) hit 16
// distinct even-bank pairs. 16*33*8 = 4224 -> pad 4352.
#define RED_OFF   (2*BUFSZ)
#define LOG_OFF   (2*BUFSZ + 4352)
#define AUX_OFF   (LOG_OFF + 4096)
#define LDS_BYTES (AUX_OFF + 128)    // 76288 -> 1 block/CU

// DPP-butterfly add (VALU pipe), row16-internal; <=1 ulp vs shfl order.
template<int CTRL>
__device__ __forceinline__ float dpp_fadd(float x) {
    const int xi = __builtin_bit_cast(int, x);
    const int pi = __builtin_amdgcn_update_dpp(0, xi, CTRL, 0xf, 0xf, true);
    return x + __builtin_bit_cast(float, pi);
}
#define DPP_XOR1  0xB1   // quad_perm(1,0,3,2)
#define DPP_XOR2  0x4E   // quad_perm(2,3,0,1)
#define DPP_ROR4  0x124  // row_ror:4
#define DPP_ROR8  0x128  // row_ror:8

// r9 structure VERBATIM (78.9 us best): 16 waves, 16 cols/wave, TWO
// barriers/iter. Ledger: every barrier-merge/phase-restructure attempt
// (r3 atomics, r4 8-wave, r6 stage-first, r7 sched_barrier, r10 super-iter)
// regressed 8-30us via spill (WRITE_SIZE canary) or exposed latency.
// r11 change ONLY: finalize distributed across all 16 waves (wave wv
// reduces rows 2wv,2wv+1 via shfl tree) instead of wave-0 serial chain.
__global__ __launch_bounds__(1024, 4) void mfma_main(
    const float* __restrict__ slots, const float* __restrict__ gamma,
    const float* __restrict__ beta,  const float* __restrict__ w1,
    const float* __restrict__ b1,    const float* __restrict__ w2,
    const float* __restrict__ b2,    const float* __restrict__ u,
    const float* __restrict__ rk,    float* __restrict__ out)
{
    extern __shared__ __align__(16) char smem[];
    float2* red    = (float2*)(smem + RED_OFF);   // [16][33] used as w*33+r
    float2* logits = (float2*)(smem + LOG_OFF);   // [512]
    unsigned long long* best = (unsigned long long*)(smem + AUX_OFF);
    int* cnts = (int*)(smem + AUX_OFF + 64);      // [8]
    int* sNK  = (int*)(smem + AUX_OFF + 96);      // [0]=need [1]=kbest

    const int t    = threadIdx.x;
    const int lane = t & 63;
    const int wv   = t >> 6;        // 0..15
    const int quad = lane >> 4;     // 0..3
    const int n16  = lane & 15;
    const int srow = t >> 5;        // 0..31 staging row
    const int seg8 = t & 31;        // 8 d's (one chunk) per staging thread

    const int colB  = wv*16 + n16;  // B-frag load column (0..255)
    const int tile0 = blockIdx.x * ITERS;

    // ---- persistent B fragments (gamma folded) + b1' = b1 + beta.W1 ----
    half8 Bh[8], Bl[8];
    float bsum = 0.f;
    #pragma unroll
    for (int ks = 0; ks < 8; ++ks) {
        const int k0 = ks*32 + quad*8;
        half8 h, l;
        #pragma unroll
        for (int j = 0; j < 8; ++j) {
            const float w  = w1[(size_t)(k0 + j)*H_ + colB];
            bsum += beta[k0 + j] * w;
            const float wg = gamma[k0 + j] * w;
            const _Float16 hh = (_Float16)wg;
            h[j] = hh;
            l[j] = (_Float16)((wg - (float)hh) * 1024.0f);
        }
        Bh[ks] = h; Bl[ks] = l;
    }
    bsum += __shfl_xor(bsum, 16, 64);
    bsum += __shfl_xor(bsum, 32, 64);
    const float b1col = b1[colB] + bsum;   // valid for col colB (lane n16)

    // redistribute epilogue constants to D layout: col = base + quad*4 + reg
    float b1p[4], w20[4], w21[4];
    #pragma unroll
    for (int reg = 0; reg < 4; ++reg) {
        const int cq = quad*4 + reg;                    // 0..15
        b1p[reg] = __shfl(b1col, cq, 64);               // from lane cq
        const int col = wv*16 + cq;
        w20[reg] = w2[2*col + 0];
        w21[reg] = w2[2*col + 1];
    }

    // LN (xhat only) + fp16 split + permuted LDS store of one 32-row tile.
    auto ln_stage = [&](const float* xr, char* buf) {
        float s = 0.f;
        #pragma unroll
        for (int j = 0; j < 8; ++j) s += xr[j];
        s = dpp_fadd<DPP_XOR1>(s);
        s = dpp_fadd<DPP_XOR2>(s);
        s = dpp_fadd<DPP_ROR4>(s);
        s = dpp_fadd<DPP_ROR8>(s);
        s += __shfl_xor(s, 16, 64);
        const float mean = s * (1.f/256.f);
        float q = 0.f;
        #pragma unroll
        for (int j = 0; j < 8; ++j) { const float d = xr[j]-mean; q += d*d; }
        q = dpp_fadd<DPP_XOR1>(q);
        q = dpp_fadd<DPP_XOR2>(q);
        q = dpp_fadd<DPP_ROR4>(q);
        q = dpp_fadd<DPP_ROR8>(q);
        q += __shfl_xor(q, 16, 64);
        const float rstd = rsqrtf(q * (1.f/256.f) + LNEPS);
        half8 hh, ll;
        #pragma unroll
        for (int jj = 0; jj < 8; ++jj) {
            const float x = (xr[jj] - mean) * rstd;
            const _Float16 xh = (_Float16)x;
            hh[jj] = xh;
            ll[jj] = (_Float16)((x - (float)xh) * 1024.0f);
        }
        const int off = srow*ROWS_ + ((seg8>>1) + 16*(seg8&1)) * 16;
        *(half8*)(buf + off)       = hh;
        *(half8*)(buf + ASZ + off) = ll;
    };

    // prologue: stage tile0 into buffer 0
    {
        const float* sp = slots + ((size_t)tile0*32 + srow)*D_ + seg8*8;
        float xr0[8];
        #pragma unroll
        for (int i4 = 0; i4 < 2; ++i4) {
            const float4 v = ((const float4*)sp)[i4];
            xr0[4*i4+0]=v.x; xr0[4*i4+1]=v.y; xr0[4*i4+2]=v.z; xr0[4*i4+3]=v.w;
        }
        ln_stage(xr0, smem);
    }
    __syncthreads();

    for (int i = 0; i < ITERS; ++i) {
        const int p = i & 1;
        const bool have_next = (i + 1 < ITERS);

        // prefetch next tile (global latency hidden under MFMA phase)
        float xr[8];
        if (have_next) {
            const float* sp = slots + ((size_t)(tile0+i+1)*32 + srow)*D_ + seg8*8;
            #pragma unroll
            for (int i4 = 0; i4 < 2; ++i4) {
                const float4 v = ((const float4*)sp)[i4];
                xr[4*i4+0]=v.x; xr[4*i4+1]=v.y; xr[4*i4+2]=v.z; xr[4*i4+3]=v.w;
            }
        }

        // ---- MFMA: 3-pass split over K=256, operands swapped:
        //      D[m=col(quad*4+reg)][n=slotrow(n16)] ----
        const char* Ah = smem + (size_t)p*BUFSZ;
        const char* Al = Ah + ASZ;
        f32x4 Ch[2], Cl[2];
        Ch[0] = (f32x4)0.f; Ch[1] = (f32x4)0.f;
        Cl[0] = (f32x4)0.f; Cl[1] = (f32x4)0.f;

        #pragma unroll
        for (int ks = 0; ks < 8; ++ks) {
            const int c   = ks*4 + quad;                    // chunk index
            const int off = ((c>>1) + 16*(c&1)) * 16;       // pos(c)*16
            const half8 ah0 = *(const half8*)(Ah +  n16     *ROWS_ + off);
            const half8 ah1 = *(const half8*)(Ah + (n16+16) *ROWS_ + off);
            const half8 al0 = *(const half8*)(Al +  n16     *ROWS_ + off);
            const half8 al1 = *(const half8*)(Al + (n16+16) *ROWS_ + off);
            Ch[0] = __builtin_amdgcn_mfma_f32_16x16x32_f16(Bh[ks], ah0, Ch[0], 0,0,0);
            Ch[1] = __builtin_amdgcn_mfma_f32_16x16x32_f16(Bh[ks], ah1, Ch[1], 0,0,0);
            Cl[0] = __builtin_amdgcn_mfma_f32_16x16x32_f16(Bl[ks], ah0, Cl[0], 0,0,0);
            Cl[1] = __builtin_amdgcn_mfma_f32_16x16x32_f16(Bl[ks], ah1, Cl[1], 0,0,0);
            Cl[0] = __builtin_amdgcn_mfma_f32_16x16x32_f16(Bh[ks], al0, Cl[0], 0,0,0);
            Cl[1] = __builtin_amdgcn_mfma_f32_16x16x32_f16(Bh[ks], al1, Cl[1], 0,0,0);
        }

        // ---- epilogue: relu + w2; reduce 4 regs in-register + 2 shfl ----
        #pragma unroll
        for (int rs = 0; rs < 2; ++rs) {
            float p0 = 0.f, p1 = 0.f;
            #pragma unroll
            for (int reg = 0; reg < 4; ++reg) {
                float hv = Ch[rs][reg] + Cl[rs][reg]*INV1024 + b1p[reg];
                hv = fmaxf(hv, 0.f);
                p0 = fmaf(hv, w20[reg], p0);
                p1 = fmaf(hv, w21[reg], p1);
            }
            p0 += __shfl_xor(p0, 16, 64); p1 += __shfl_xor(p1, 16, 64);
            p0 += __shfl_xor(p0, 32, 64); p1 += __shfl_xor(p1, 32, 64);
            if (lane < 16)                       // quad 0 holds the total
                red[wv*33 + rs*16 + n16] = make_float2(p0, p1);
        }
        __syncthreads();

        // ---- finalize (all 16 waves): wave wv reduces rows 2wv,2wv+1 ----
        // lanes 0..15: row 2wv, w=lane; lanes 16..31: row 2wv+1, w=lane-16.
        // shfl tree masks 1,2,4,8 stay within each 16-lane group.
        if (lane < 32) {
            const int row = 2*wv + (lane >> 4);
            const int w   = lane & 15;
            float2 v = red[w*33 + row];
            #pragma unroll
            for (int m = 1; m <= 8; m <<= 1) {
                v.x += __shfl_xor(v.x, m, 64);
                v.y += __shfl_xor(v.y, m, 64);
            }
            if ((lane & 15) == 0)
                logits[i*32 + row] = v;
        }
        // ---- stage next tile into other buffer ----
        if (have_next)
            ln_stage(xr, smem + (size_t)(p^1)*BUFSZ);
        __syncthreads();
    }

    // ==== fused combine: gumbel decision, soft prob, lower-bound fixup ====
    bool keep = false;
    if (t < 512) {
        const int k = t;
        const int row = blockIdx.x*K_ + k;
        const float2 lg = logits[k];
        const float l0 = b2[0] + lg.x;
        const float l1 = b2[1] + lg.y;
        const float2 uu = ((const float2*)u)[row];
        const float g0 = -logf(-logf(uu.x));
        const float g1 = -logf(-logf(uu.y));
        keep = (l1 + g1) > (l0 + g0);
        out[NROWS + row] = 1.f / (1.f + expf(l0 - l1));

        unsigned long long comb = 0;
        if (!keep)
            comb = ((unsigned long long)__float_as_uint(rk[row]) << 32)
                 | (unsigned)(K_ - 1 - k);
        const int wcount = __popcll(__ballot(keep));
        #pragma unroll
        for (int off = 32; off >= 1; off >>= 1) {
            const unsigned long long o = __shfl_xor(comb, off, 64);
            if (o > comb) comb = o;
        }
        if ((k & 63) == 0) { best[k >> 6] = comb; cnts[k >> 6] = wcount; }
    }
    __syncthreads();
    if (t == 0) {
        int tot = 0; unsigned long long bc = 0;
        #pragma unroll
        for (int w = 0; w < 8; ++w) { tot += cnts[w]; if (best[w] > bc) bc = best[w]; }
        sNK[0] = (tot == 0);
        sNK[1] = (K_ - 1) - (int)(bc & 0xffffffffu);
    }
    __syncthreads();
    if (t < 512) {
        const int row = blockIdx.x*K_ + t;
        const bool m = keep || (sNK[0] && (t == sNK[1]));
        out[row] = m ? 1.f : 0.f;
    }
}

extern "C" void kernel_launch(void* const* d_in, const int* in_sizes, int n_in,
                              void* d_out, int out_size, void* d_ws, size_t ws_size,
                              hipStream_t stream) {
    const float* slots = (const float*)d_in[0];
    const float* gamma = (const float*)d_in[1];
    const float* beta  = (const float*)d_in[2];
    const float* w1    = (const float*)d_in[3];
    const float* b1    = (const float*)d_in[4];
    const float* w2    = (const float*)d_in[5];
    const float* b2    = (const float*)d_in[6];
    const float* u     = (const float*)d_in[7];
    const float* rk    = (const float*)d_in[8];
    float* out = (float*)d_out;

    hipLaunchKernelGGL(mfma_main, dim3(B_), dim3(1024), LDS_BYTES, stream,
                       slots, gamma, beta, w1, b1, w2, b2, u, rk, out);
}